// Round 8
// baseline (670.238 us; speedup 1.0000x reference)
//
#include <hip/hip_runtime.h>
#include <hip/hip_bf16.h>

// ---------------------------------------------------------------------------
// GraphSageLinkPred round 8:
//  - aggregate_bf16: 8 gathers in flight per 16-lane group (was 2) — the
//    kernel was gather-latency-bound (VALUBusy 21%, HBM 38%, occ 56%)
//  - unchanged: MFMA input fusion, bucketed CSR build, merged P-layer GEMM,
//    hi/lo weights, linearity reorder, pair-unpack predict
// ---------------------------------------------------------------------------

typedef unsigned short u16;
typedef unsigned int u32;
typedef __attribute__((ext_vector_type(8))) short bf16x8;
typedef __attribute__((ext_vector_type(4))) float f32x4;

#define H 128
#define GP 40            // gemm LDS pitch in u16

#define NBP_MAX 128      // (30000>>8)+1 = 118
#define NBU_MAX 400      // (100000>>8)+1 = 391
#define PCHUNK 8192
#define SHIFT_P 17
#define SHIFT_U 15
#define CAP_P 9216
#define CAP_U 3072

__device__ __forceinline__ float bf2f(u16 u) {
    return __uint_as_float(((u32)u) << 16);
}
__device__ __forceinline__ u16 f2bf(float f) {        // RNE
    u32 u = __float_as_uint(f);
    return (u16)((u + 0x7fffu + ((u >> 16) & 1u)) >> 16);
}

// ---- split fp32 -> bf16 hi + lo --------------------------------------------
__global__ __launch_bounds__(256) void split_x(
    const float* __restrict__ x, u16* __restrict__ xh, u16* __restrict__ xl,
    int nelem)
{
    int i = (blockIdx.x * 256 + threadIdx.x) * 4;
    if (i >= nelem) return;
    float4 v = *(const float4*)&x[i];
    u16 h[4], l[4];
    h[0] = f2bf(v.x); l[0] = f2bf(v.x - bf2f(h[0]));
    h[1] = f2bf(v.y); l[1] = f2bf(v.y - bf2f(h[1]));
    h[2] = f2bf(v.z); l[2] = f2bf(v.z - bf2f(h[2]));
    h[3] = f2bf(v.w); l[3] = f2bf(v.w - bf2f(h[3]));
    *(int2*)&xh[i] = *(const int2*)&h[0];
    *(int2*)&xl[i] = *(const int2*)&l[0];
}

// ---- fuse weight prep: W[F][H] fp32 -> WF[2][H][F] bf16 (hi, lo; c-major) --
template<int F>
__global__ __launch_bounds__(256) void prep_fuse_w(
    const float* __restrict__ W, u16* __restrict__ WF)
{
    int idx = blockIdx.x * 256 + threadIdx.x;
    if (idx >= 128 * F) return;
    int c = idx / F, k = idx % F;
    float v = W[(size_t)k * H + c];
    u16 hi = f2bf(v);
    u16 lo = f2bf(v - bf2f(hi));
    WF[idx] = hi;
    WF[128 * F + idx] = lo;
}

// ---- fused input GEMM: out = bf16( x@W + b + emb[ids] ) --------------------
template<int F>
__global__ __launch_bounds__(512) void fuse_gemm(
    const u16* __restrict__ xh, const u16* __restrict__ xl,
    const u16* __restrict__ Wf, const float* __restrict__ b,
    const float* __restrict__ emb, const int* __restrict__ ids,
    u16* __restrict__ out, int n)
{
    __shared__ u16 Xh_s[128 * GP];
    __shared__ u16 Xl_s[128 * GP];
    __shared__ u16 Wh_s[128 * GP];
    __shared__ u16 Wl_s[128 * GP];
    const int t = threadIdx.x;
    const int lane = t & 63;
    const int w = t >> 6;
    const int rg = w >> 1;
    const int cg = w & 1;
    const int r0 = blockIdx.x * 128;

    f32x4 acc[2][4];
    #pragma unroll
    for (int i = 0; i < 2; i++)
        #pragma unroll
        for (int j = 0; j < 4; j++) acc[i][j] = (f32x4){0.f, 0.f, 0.f, 0.f};

    const int row = t >> 2, q = t & 3;

    #pragma unroll
    for (int kc = 0; kc < F / 32; kc++) {
        __syncthreads();
        {
            int grow = r0 + row;
            int4 vh = {0, 0, 0, 0}, vl = {0, 0, 0, 0};
            if (grow < n) {
                vh = *(const int4*)&xh[(size_t)grow * F + kc * 32 + q * 8];
                vl = *(const int4*)&xl[(size_t)grow * F + kc * 32 + q * 8];
            }
            *(int4*)&Xh_s[row * GP + q * 8] = vh;
            *(int4*)&Xl_s[row * GP + q * 8] = vl;
            *(int4*)&Wh_s[row * GP + q * 8] =
                *(const int4*)&Wf[(size_t)row * F + kc * 32 + q * 8];
            *(int4*)&Wl_s[row * GP + q * 8] =
                *(const int4*)&Wf[(size_t)128 * F + (size_t)row * F + kc * 32 + q * 8];
        }
        __syncthreads();
        const int a0off = (rg * 32 + (lane & 15)) * GP + (lane >> 4) * 8;
        const int a1off = a0off + 16 * GP;
        bf16x8 ah0 = *(const bf16x8*)&Xh_s[a0off];
        bf16x8 ah1 = *(const bf16x8*)&Xh_s[a1off];
        bf16x8 al0 = *(const bf16x8*)&Xl_s[a0off];
        bf16x8 al1 = *(const bf16x8*)&Xl_s[a1off];
        #pragma unroll
        for (int ct = 0; ct < 4; ct++) {
            int boff = (cg * 64 + ct * 16 + (lane & 15)) * GP + (lane >> 4) * 8;
            bf16x8 bh = *(const bf16x8*)&Wh_s[boff];
            bf16x8 bl = *(const bf16x8*)&Wl_s[boff];
            acc[0][ct] = __builtin_amdgcn_mfma_f32_16x16x32_bf16(ah0, bh, acc[0][ct], 0, 0, 0);
            acc[0][ct] = __builtin_amdgcn_mfma_f32_16x16x32_bf16(ah0, bl, acc[0][ct], 0, 0, 0);
            acc[0][ct] = __builtin_amdgcn_mfma_f32_16x16x32_bf16(al0, bh, acc[0][ct], 0, 0, 0);
            acc[1][ct] = __builtin_amdgcn_mfma_f32_16x16x32_bf16(ah1, bh, acc[1][ct], 0, 0, 0);
            acc[1][ct] = __builtin_amdgcn_mfma_f32_16x16x32_bf16(ah1, bl, acc[1][ct], 0, 0, 0);
            acc[1][ct] = __builtin_amdgcn_mfma_f32_16x16x32_bf16(al1, bh, acc[1][ct], 0, 0, 0);
        }
    }
    #pragma unroll
    for (int rt = 0; rt < 2; rt++) {
        #pragma unroll
        for (int j = 0; j < 4; j++) {
            int roww = r0 + rg * 32 + rt * 16 + (lane >> 4) * 4 + j;
            if (roww < n) {
                int id = ids[roww];
                #pragma unroll
                for (int ct = 0; ct < 4; ct++) {
                    int col = cg * 64 + ct * 16 + (lane & 15);
                    float v = acc[rt][ct][j] + b[col] + emb[(size_t)id * H + col];
                    out[(size_t)roww * H + col] = f2bf(v);
                }
            }
        }
    }
}

// ---- weight prep (layer weights) -------------------------------------------
__global__ __launch_bounds__(256) void prep_weights(
    const float* __restrict__ Wl, const float* __restrict__ Wr,
    u16* __restrict__ WT)
{
    int idx = blockIdx.x * 256 + threadIdx.x;       // 12*128*128
    if (idx >= 12 * H * H) return;
    int m = idx >> 14;
    int k = idx & 127;
    int c = (idx >> 7) & 127;
    const float* src = (m < 6) ? (Wl + (size_t)m * H * H) : (Wr + (size_t)(m - 6) * H * H);
    float v = src[(size_t)k * H + c];
    u16 hi = f2bf(v);
    u16 lo = f2bf(v - bf2f(hi));
    size_t base = (size_t)m * 2 * H * H;
    WT[base + (size_t)c * H + k] = hi;
    WT[base + H * H + (size_t)c * H + k] = lo;
}

// ---- CSR build: two-level bucket partition ---------------------------------
__global__ __launch_bounds__(256) void bucket_hist(
    const int* __restrict__ esrc, const int* __restrict__ edst, int E,
    int* __restrict__ bh_p, int* __restrict__ bh_u, int nbp, int nbu)
{
    __shared__ int hp[NBP_MAX], hu[NBU_MAX];
    const int t = threadIdx.x;
    for (int i = t; i < nbp; i += 256) hp[i] = 0;
    for (int i = t; i < nbu; i += 256) hu[i] = 0;
    __syncthreads();
    const int e0 = blockIdx.x * PCHUNK;
    #pragma unroll 4
    for (int i = 0; i < PCHUNK / 256; i++) {
        int e = e0 + i * 256 + t;
        if (e < E) {
            atomicAdd(&hp[edst[e] >> 8], 1);
            atomicAdd(&hu[esrc[e] >> 8], 1);
        }
    }
    __syncthreads();
    for (int i = t; i < nbp; i += 256) if (hp[i]) atomicAdd(&bh_p[i], hp[i]);
    for (int i = t; i < nbu; i += 256) if (hu[i]) atomicAdd(&bh_u[i], hu[i]);
}

__global__ __launch_bounds__(512) void bucket_scan(
    const int* __restrict__ bh_p, const int* __restrict__ bh_u,
    int* __restrict__ bs_p, int* __restrict__ bs_u,
    int* __restrict__ cur_p, int* __restrict__ cur_u, int nbp, int nbu)
{
    __shared__ int sh[512];
    const int t = threadIdx.x;
    int v = (t < nbp) ? bh_p[t] : 0;
    sh[t] = v; __syncthreads();
    for (int off = 1; off < 512; off <<= 1) {
        int x = (t >= off) ? sh[t - off] : 0;
        __syncthreads();
        sh[t] += x;
        __syncthreads();
    }
    if (t < nbp) { int e = sh[t] - v; bs_p[t] = e; cur_p[t] = e; }
    if (t == 0) bs_p[nbp] = sh[511];
    __syncthreads();
    v = (t < nbu) ? bh_u[t] : 0;
    sh[t] = v; __syncthreads();
    for (int off = 1; off < 512; off <<= 1) {
        int x = (t >= off) ? sh[t - off] : 0;
        __syncthreads();
        sh[t] += x;
        __syncthreads();
    }
    if (t < nbu) { int e = sh[t] - v; bs_u[t] = e; cur_u[t] = e; }
    if (t == 0) bs_u[nbu] = sh[511];
}

__global__ __launch_bounds__(256) void partition_edges(
    const int* __restrict__ esrc, const int* __restrict__ edst, int E,
    int* __restrict__ cur_p, int* __restrict__ cur_u,
    u32* __restrict__ pp, u32* __restrict__ pu, int nbp, int nbu)
{
    __shared__ int hp[NBP_MAX], hu[NBU_MAX];
    __shared__ int bp[NBP_MAX], bu[NBU_MAX];
    const int t = threadIdx.x;
    const int e0 = blockIdx.x * PCHUNK;
    for (int i = t; i < nbp; i += 256) hp[i] = 0;
    for (int i = t; i < nbu; i += 256) hu[i] = 0;
    __syncthreads();
    #pragma unroll 4
    for (int i = 0; i < PCHUNK / 256; i++) {
        int e = e0 + i * 256 + t;
        if (e < E) {
            atomicAdd(&hp[edst[e] >> 8], 1);
            atomicAdd(&hu[esrc[e] >> 8], 1);
        }
    }
    __syncthreads();
    for (int i = t; i < nbp; i += 256) { int c = hp[i]; bp[i] = c ? atomicAdd(&cur_p[i], c) : 0; }
    for (int i = t; i < nbu; i += 256) { int c = hu[i]; bu[i] = c ? atomicAdd(&cur_u[i], c) : 0; }
    __syncthreads();
    for (int i = t; i < nbp; i += 256) hp[i] = 0;
    for (int i = t; i < nbu; i += 256) hu[i] = 0;
    __syncthreads();
    #pragma unroll 4
    for (int i = 0; i < PCHUNK / 256; i++) {
        int e = e0 + i * 256 + t;
        if (e < E) {
            int s = esrc[e], d = edst[e];
            int lp = atomicAdd(&hp[d >> 8], 1);
            pp[bp[d >> 8] + lp] = ((u32)(d & 255) << SHIFT_P) | (u32)s;
            int lu = atomicAdd(&hu[s >> 8], 1);
            pu[bu[s >> 8] + lu] = ((u32)(s & 255) << SHIFT_U) | (u32)d;
        }
    }
}

template<int SHIFT, int CAP>
__global__ __launch_bounds__(256) void build_csr(
    const u32* __restrict__ packed, const int* __restrict__ bktstart,
    int* __restrict__ col, int* __restrict__ rp, int n_nodes, int E)
{
    __shared__ int sh[256];
    __shared__ int excl_s[256];
    __shared__ int cur[256];
    __shared__ int buf[CAP];
    const int b = blockIdx.x, t = threadIdx.x;
    const int s0 = bktstart[b], s1 = bktstart[b + 1];
    const int n = s1 - s0;
    sh[t] = 0; cur[t] = 0;
    __syncthreads();
    for (int i = t; i < n; i += 256) {
        int dl = (int)(packed[s0 + i] >> SHIFT);
        atomicAdd(&sh[dl], 1);
    }
    __syncthreads();
    int v = sh[t];
    __syncthreads();
    for (int off = 1; off < 256; off <<= 1) {
        int x = (t >= off) ? sh[t - off] : 0;
        __syncthreads();
        sh[t] += x;
        __syncthreads();
    }
    int excl = sh[t] - v;
    excl_s[t] = excl;
    int d = b * 256 + t;
    if (d < n_nodes) rp[d] = s0 + excl;
    if (b == gridDim.x - 1 && t == 0) rp[n_nodes] = E;
    __syncthreads();
    for (int i = t; i < n; i += 256) {
        u32 pv = packed[s0 + i];
        int dl = (int)(pv >> SHIFT);
        int pos = excl_s[dl] + atomicAdd(&cur[dl], 1);
        buf[pos] = (int)(pv & ((1u << SHIFT) - 1u));
    }
    __syncthreads();
    for (int i = t; i < n; i += 256) col[s0 + i] = buf[i];
}

// ---- mean aggregation: 16-lane group per row, 8 gathers in flight ----------
__global__ __launch_bounds__(256) void aggregate_bf16(
    const u16* __restrict__ feat, const int* __restrict__ rowptr,
    const int* __restrict__ col, u16* __restrict__ out, int nrows)
{
    const int grp = threadIdx.x >> 4;
    const int sl  = threadIdx.x & 15;
    const int r = blockIdx.x * 16 + grp;
    if (r >= nrows) return;
    const int s0 = rowptr[r], s1 = rowptr[r + 1];
    float aL[4] = {0.f, 0.f, 0.f, 0.f};
    float aH[4] = {0.f, 0.f, 0.f, 0.f};
    const u16* base = feat + (size_t)sl * 8;
    int e = s0;
    // 8-deep main loop: 8 independent 256B row gathers in flight
    for (; e + 8 <= s1; e += 8) {
        int c[8];
        #pragma unroll
        for (int k = 0; k < 8; k++) c[k] = col[e + k];
        uint4 v[8];
        #pragma unroll
        for (int k = 0; k < 8; k++) v[k] = *(const uint4*)(base + (size_t)c[k] * H);
        #pragma unroll
        for (int k = 0; k < 8; k++) {
            u32 w;
            w = v[k].x; aL[0] += __uint_as_float(w << 16); aH[0] += __uint_as_float(w & 0xffff0000u);
            w = v[k].y; aL[1] += __uint_as_float(w << 16); aH[1] += __uint_as_float(w & 0xffff0000u);
            w = v[k].z; aL[2] += __uint_as_float(w << 16); aH[2] += __uint_as_float(w & 0xffff0000u);
            w = v[k].w; aL[3] += __uint_as_float(w << 16); aH[3] += __uint_as_float(w & 0xffff0000u);
        }
    }
    // 2-deep remainder
    for (; e + 2 <= s1; e += 2) {
        int c0 = col[e], c1 = col[e + 1];
        uint4 v0 = *(const uint4*)(base + (size_t)c0 * H);
        uint4 v1 = *(const uint4*)(base + (size_t)c1 * H);
        u32 w;
        w = v0.x; aL[0] += __uint_as_float(w << 16); aH[0] += __uint_as_float(w & 0xffff0000u);
        w = v0.y; aL[1] += __uint_as_float(w << 16); aH[1] += __uint_as_float(w & 0xffff0000u);
        w = v0.z; aL[2] += __uint_as_float(w << 16); aH[2] += __uint_as_float(w & 0xffff0000u);
        w = v0.w; aL[3] += __uint_as_float(w << 16); aH[3] += __uint_as_float(w & 0xffff0000u);
        w = v1.x; aL[0] += __uint_as_float(w << 16); aH[0] += __uint_as_float(w & 0xffff0000u);
        w = v1.y; aL[1] += __uint_as_float(w << 16); aH[1] += __uint_as_float(w & 0xffff0000u);
        w = v1.z; aL[2] += __uint_as_float(w << 16); aH[2] += __uint_as_float(w & 0xffff0000u);
        w = v1.w; aL[3] += __uint_as_float(w << 16); aH[3] += __uint_as_float(w & 0xffff0000u);
    }
    if (e < s1) {
        int c0 = col[e];
        uint4 v0 = *(const uint4*)(base + (size_t)c0 * H);
        u32 w;
        w = v0.x; aL[0] += __uint_as_float(w << 16); aH[0] += __uint_as_float(w & 0xffff0000u);
        w = v0.y; aL[1] += __uint_as_float(w << 16); aH[1] += __uint_as_float(w & 0xffff0000u);
        w = v0.z; aL[2] += __uint_as_float(w << 16); aH[2] += __uint_as_float(w & 0xffff0000u);
        w = v0.w; aL[3] += __uint_as_float(w << 16); aH[3] += __uint_as_float(w & 0xffff0000u);
    }
    float inv = 1.f / (float)max(s1 - s0, 1);
    u16 o[8];
    #pragma unroll
    for (int j = 0; j < 4; j++) {
        o[2 * j]     = f2bf(aL[j] * inv);
        o[2 * j + 1] = f2bf(aH[j] * inv);
    }
    *(int4*)&out[(size_t)r * H + sl * 8] = *(const int4*)&o[0];
}

// ---- merged P-side layer GEMM ----------------------------------------------
// T    = XP @ Wl1                       (feeds the U-side aggregation)
// XPn  = AGG @ Wl0 + XP @ Wr0 + bias    (optional relu)
__global__ __launch_bounds__(512) void gemm_p_layer(
    const u16* __restrict__ XP, const u16* __restrict__ AGG,
    const u16* __restrict__ Wl0, const u16* __restrict__ Wr0,
    const u16* __restrict__ Wl1, const float* __restrict__ bias,
    u16* __restrict__ T, u16* __restrict__ XPn, int M, int relu)
{
    __shared__ u16 As[2][H * GP];        // [0]=AGG, [1]=XP
    __shared__ u16 Ws[6][H * GP];        // Wl0 h,l | Wr0 h,l | Wl1 h,l
    const int t = threadIdx.x;
    const int lane = t & 63;
    const int w = t >> 6;
    const int rg = w >> 1;
    const int cg = w & 1;
    const int r0 = blockIdx.x * 128;

    f32x4 accP[2][4], accT[2][4];
    #pragma unroll
    for (int i = 0; i < 2; i++)
        #pragma unroll
        for (int j = 0; j < 4; j++) {
            accP[i][j] = (f32x4){0.f, 0.f, 0.f, 0.f};
            accT[i][j] = (f32x4){0.f, 0.f, 0.f, 0.f};
        }

    const int srow = t >> 2;
    const int sq = t & 3;

    for (int kc = 0; kc < 4; kc++) {
        const int k0 = kc * 32;
        __syncthreads();
        {
            const int grow = r0 + srow;
            const bool ok = grow < M;
            int4 va = {0, 0, 0, 0}, vx = {0, 0, 0, 0};
            if (ok) {
                va = *(const int4*)(AGG + (size_t)grow * H + k0 + sq * 8);
                vx = *(const int4*)(XP  + (size_t)grow * H + k0 + sq * 8);
            }
            *(int4*)&As[0][srow * GP + sq * 8] = va;
            *(int4*)&As[1][srow * GP + sq * 8] = vx;
            const size_t woff = (size_t)srow * H + k0 + sq * 8;
            *(int4*)&Ws[0][srow * GP + sq * 8] = *(const int4*)(Wl0 + woff);
            *(int4*)&Ws[1][srow * GP + sq * 8] = *(const int4*)(Wl0 + H * H + woff);
            *(int4*)&Ws[2][srow * GP + sq * 8] = *(const int4*)(Wr0 + woff);
            *(int4*)&Ws[3][srow * GP + sq * 8] = *(const int4*)(Wr0 + H * H + woff);
            *(int4*)&Ws[4][srow * GP + sq * 8] = *(const int4*)(Wl1 + woff);
            *(int4*)&Ws[5][srow * GP + sq * 8] = *(const int4*)(Wl1 + H * H + woff);
        }
        __syncthreads();
        const int a0off = (rg * 32 + (lane & 15)) * GP + (lane >> 4) * 8;
        const int a1off = a0off + 16 * GP;
        bf16x8 ag0 = *(const bf16x8*)&As[0][a0off];
        bf16x8 ag1 = *(const bf16x8*)&As[0][a1off];
        bf16x8 xf0 = *(const bf16x8*)&As[1][a0off];
        bf16x8 xf1 = *(const bf16x8*)&As[1][a1off];
        #pragma unroll
        for (int hl = 0; hl < 2; hl++) {
            #pragma unroll
            for (int ct = 0; ct < 4; ct++) {
                const int boff = (cg * 64 + ct * 16 + (lane & 15)) * GP + (lane >> 4) * 8;
                bf16x8 b0 = *(const bf16x8*)&Ws[hl][boff];      // Wl0
                bf16x8 b1 = *(const bf16x8*)&Ws[2 + hl][boff];  // Wr0
                bf16x8 b2 = *(const bf16x8*)&Ws[4 + hl][boff];  // Wl1
                accP[0][ct] = __builtin_amdgcn_mfma_f32_16x16x32_bf16(ag0, b0, accP[0][ct], 0, 0, 0);
                accP[1][ct] = __builtin_amdgcn_mfma_f32_16x16x32_bf16(ag1, b0, accP[1][ct], 0, 0, 0);
                accP[0][ct] = __builtin_amdgcn_mfma_f32_16x16x32_bf16(xf0, b1, accP[0][ct], 0, 0, 0);
                accP[1][ct] = __builtin_amdgcn_mfma_f32_16x16x32_bf16(xf1, b1, accP[1][ct], 0, 0, 0);
                accT[0][ct] = __builtin_amdgcn_mfma_f32_16x16x32_bf16(xf0, b2, accT[0][ct], 0, 0, 0);
                accT[1][ct] = __builtin_amdgcn_mfma_f32_16x16x32_bf16(xf1, b2, accT[1][ct], 0, 0, 0);
            }
        }
    }
    #pragma unroll
    for (int rt = 0; rt < 2; rt++) {
        #pragma unroll
        for (int ct = 0; ct < 4; ct++) {
            #pragma unroll
            for (int j = 0; j < 4; j++) {
                int row = r0 + rg * 32 + rt * 16 + (lane >> 4) * 4 + j;
                int col = cg * 64 + ct * 16 + (lane & 15);
                if (row < M) {
                    T[(size_t)row * H + col] = f2bf(accT[rt][ct][j]);
                    float v = accP[rt][ct][j] + bias[col];
                    if (relu && v < 0.f) v = 0.f;
                    XPn[(size_t)row * H + col] = f2bf(v);
                }
            }
        }
    }
}

// ---- U-side MFMA GEMM: C = A@W + D + bias (relu) ---------------------------
__global__ __launch_bounds__(512, 4) void gemm_u_layer(
    const u16* __restrict__ A1, const u16* __restrict__ W1,
    const u16* __restrict__ D, const float* __restrict__ bias,
    u16* __restrict__ C, int M, int relu)
{
    __shared__ u16 As[H * GP];
    __shared__ u16 Ws[2][H * GP];
    const int t = threadIdx.x;
    const int lane = t & 63;
    const int w = t >> 6;
    const int rg = w >> 1;
    const int cg = w & 1;
    const int r0 = blockIdx.x * 128;

    f32x4 acc[2][4];
    #pragma unroll
    for (int i = 0; i < 2; i++)
        #pragma unroll
        for (int j = 0; j < 4; j++) acc[i][j] = (f32x4){0.f, 0.f, 0.f, 0.f};

    const int srow = t >> 2;
    const int sq = t & 3;

    for (int kc = 0; kc < 4; kc++) {
        const int k0 = kc * 32;
        __syncthreads();
        {
            const int grow = r0 + srow;
            int4 v = {0, 0, 0, 0};
            if (grow < M) v = *(const int4*)(A1 + (size_t)grow * H + k0 + sq * 8);
            *(int4*)&As[srow * GP + sq * 8] = v;
            const size_t woff = (size_t)srow * H + k0 + sq * 8;
            *(int4*)&Ws[0][srow * GP + sq * 8] = *(const int4*)(W1 + woff);
            *(int4*)&Ws[1][srow * GP + sq * 8] = *(const int4*)(W1 + H * H + woff);
        }
        __syncthreads();
        const int a0off = (rg * 32 + (lane & 15)) * GP + (lane >> 4) * 8;
        bf16x8 af0 = *(const bf16x8*)&As[a0off];
        bf16x8 af1 = *(const bf16x8*)&As[a0off + 16 * GP];
        #pragma unroll
        for (int hl = 0; hl < 2; hl++) {
            #pragma unroll
            for (int ct = 0; ct < 4; ct++) {
                bf16x8 bf = *(const bf16x8*)&Ws[hl][(cg * 64 + ct * 16 + (lane & 15)) * GP + (lane >> 4) * 8];
                acc[0][ct] = __builtin_amdgcn_mfma_f32_16x16x32_bf16(af0, bf, acc[0][ct], 0, 0, 0);
                acc[1][ct] = __builtin_amdgcn_mfma_f32_16x16x32_bf16(af1, bf, acc[1][ct], 0, 0, 0);
            }
        }
    }
    #pragma unroll
    for (int rt = 0; rt < 2; rt++) {
        #pragma unroll
        for (int ct = 0; ct < 4; ct++) {
            #pragma unroll
            for (int j = 0; j < 4; j++) {
                int row = r0 + rg * 32 + rt * 16 + (lane >> 4) * 4 + j;
                int col = cg * 64 + ct * 16 + (lane & 15);
                if (row < M) {
                    float v = acc[rt][ct][j] + bias[col] + bf2f(D[(size_t)row * H + col]);
                    if (relu && v < 0.f) v = 0.f;
                    C[(size_t)row * H + col] = f2bf(v);
                }
            }
        }
    }
}

// ---- link prediction: 16-lane group per pair, pair-unpack dot --------------
__global__ __launch_bounds__(256) void predict(
    const u16* __restrict__ xu, const u16* __restrict__ xp,
    const int* __restrict__ ls, const int* __restrict__ ld,
    float* __restrict__ out, int EL)
{
    int w = (int)(blockIdx.x * 16 + (threadIdx.x >> 4));
    int sl = threadIdx.x & 15;
    if (w >= EL) return;
    int u = ls[w], p = ld[w];
    uint4 av = *(const uint4*)&xu[(size_t)u * H + sl * 8];
    uint4 bv = *(const uint4*)&xp[(size_t)p * H + sl * 8];
    float d = 0.f;
    u32 x, y;
    x = av.x; y = bv.x;
    d += __uint_as_float(x << 16) * __uint_as_float(y << 16);
    d += __uint_as_float(x & 0xffff0000u) * __uint_as_float(y & 0xffff0000u);
    x = av.y; y = bv.y;
    d += __uint_as_float(x << 16) * __uint_as_float(y << 16);
    d += __uint_as_float(x & 0xffff0000u) * __uint_as_float(y & 0xffff0000u);
    x = av.z; y = bv.z;
    d += __uint_as_float(x << 16) * __uint_as_float(y << 16);
    d += __uint_as_float(x & 0xffff0000u) * __uint_as_float(y & 0xffff0000u);
    x = av.w; y = bv.w;
    d += __uint_as_float(x << 16) * __uint_as_float(y << 16);
    d += __uint_as_float(x & 0xffff0000u) * __uint_as_float(y & 0xffff0000u);
    #pragma unroll
    for (int off = 8; off > 0; off >>= 1) d += __shfl_xor(d, off, 16);
    if (sl == 0) out[w] = d;
}

// ---------------------------------------------------------------------------
extern "C" void kernel_launch(void* const* d_in, const int* in_sizes, int n_in,
                              void* d_out, int out_size, void* d_ws, size_t ws_size,
                              hipStream_t stream)
{
    const float* user_x = (const float*)d_in[0];
    const float* prod_x = (const float*)d_in[1];
    const float* uemb   = (const float*)d_in[2];
    const float* pemb   = (const float*)d_in[3];
    const float* ulw    = (const float*)d_in[4];
    const float* ulb    = (const float*)d_in[5];
    const float* plw    = (const float*)d_in[6];
    const float* plb    = (const float*)d_in[7];
    const float* Wl     = (const float*)d_in[8];
    const float* blv    = (const float*)d_in[9];
    const float* Wr     = (const float*)d_in[10];
    const int* uid  = (const int*)d_in[11];
    const int* pid  = (const int*)d_in[12];
    const int* esrc = (const int*)d_in[13];
    const int* edst = (const int*)d_in[14];
    const int* lsrc = (const int*)d_in[15];
    const int* ldst = (const int*)d_in[16];
    float* out = (float*)d_out;

    const int NU = in_sizes[11];
    const int NP = in_sizes[12];
    const int E  = in_sizes[13];
    const int EL = in_sizes[15];
    const int nbp = (NP >> 8) + 1;      // 118
    const int nbu = (NU >> 8) + 1;      // 391
    const int UF = in_sizes[4] / H;     // 32
    const int PF = in_sizes[6] / H;     // 64

    char* ws = (char*)d_ws;
    size_t off = 0;
    auto alloc = [&](size_t b) -> char* {
        char* p = ws + off;
        off += (b + 511) & ~(size_t)511;
        return p;
    };
    u16* XU[2]  = { (u16*)alloc((size_t)NU * H * 2), (u16*)alloc((size_t)NU * H * 2) };
    u16* XP[2]  = { (u16*)alloc((size_t)NP * H * 2), (u16*)alloc((size_t)NP * H * 2) };
    u16* AGG_P  = (u16*)alloc((size_t)NP * H * 2);
    u16* AGG_U  = (u16*)alloc((size_t)NU * H * 2);
    u16* T      = (u16*)alloc((size_t)NP * H * 2);
    u16* WT     = (u16*)alloc((size_t)12 * 2 * H * H * 2);
    u16* XHU    = (u16*)alloc((size_t)NU * UF * 2);
    u16* XLU    = (u16*)alloc((size_t)NU * UF * 2);
    u16* XHP    = (u16*)alloc((size_t)NP * PF * 2);
    u16* XLP    = (u16*)alloc((size_t)NP * PF * 2);
    u16* WFU    = (u16*)alloc((size_t)2 * H * UF * 2);
    u16* WFP    = (u16*)alloc((size_t)2 * H * PF * 2);
    int* rp_dst  = (int*)alloc((size_t)(NP + 1) * 4);
    int* rp_src  = (int*)alloc((size_t)(NU + 1) * 4);
    int* col_dst = (int*)alloc((size_t)E * 4);
    int* col_src = (int*)alloc((size_t)E * 4);
    u32* pp      = (u32*)alloc((size_t)E * 4);
    u32* pu      = (u32*)alloc((size_t)E * 4);
    int* bh_p    = (int*)alloc((size_t)NBP_MAX * 4);
    int* bs_p    = (int*)alloc((size_t)(NBP_MAX + 1) * 4);
    int* cur_p   = (int*)alloc((size_t)NBP_MAX * 4);
    int* bh_u    = (int*)alloc((size_t)NBU_MAX * 4);
    int* bs_u    = (int*)alloc((size_t)(NBU_MAX + 1) * 4);
    int* cur_u   = (int*)alloc((size_t)NBU_MAX * 4);
    (void)ws_size; (void)n_in; (void)out_size;

    // ---- 1. input fusion (MFMA) + weight prep ----
    split_x<<<(NU * UF / 4 + 255) / 256, 256, 0, stream>>>(user_x, XHU, XLU, NU * UF);
    split_x<<<(NP * PF / 4 + 255) / 256, 256, 0, stream>>>(prod_x, XHP, XLP, NP * PF);
    prep_fuse_w<32><<<(128 * 32 + 255) / 256, 256, 0, stream>>>(ulw, WFU);
    prep_fuse_w<64><<<(128 * 64 + 255) / 256, 256, 0, stream>>>(plw, WFP);
    prep_weights<<<(12 * H * H + 255) / 256, 256, 0, stream>>>(Wl, Wr, WT);
    fuse_gemm<32><<<(NU + 127) / 128, 512, 0, stream>>>(XHU, XLU, WFU, ulb, uemb, uid, XU[0], NU);
    fuse_gemm<64><<<(NP + 127) / 128, 512, 0, stream>>>(XHP, XLP, WFP, plb, pemb, pid, XP[0], NP);

    // ---- 2. CSR build ----
    hipMemsetAsync(bh_p, 0, (size_t)nbp * 4, stream);
    hipMemsetAsync(bh_u, 0, (size_t)nbu * 4, stream);
    const int nchunk = (E + PCHUNK - 1) / PCHUNK;
    bucket_hist<<<nchunk, 256, 0, stream>>>(esrc, edst, E, bh_p, bh_u, nbp, nbu);
    bucket_scan<<<1, 512, 0, stream>>>(bh_p, bh_u, bs_p, bs_u, cur_p, cur_u, nbp, nbu);
    partition_edges<<<nchunk, 256, 0, stream>>>(esrc, edst, E, cur_p, cur_u, pp, pu, nbp, nbu);
    build_csr<SHIFT_P, CAP_P><<<nbp, 256, 0, stream>>>(pp, bs_p, col_dst, rp_dst, NP, E);
    build_csr<SHIFT_U, CAP_U><<<nbu, 256, 0, stream>>>(pu, bs_u, col_src, rp_src, NU, E);

    // ---- 3. layers ----
    // T   = xp@Wl[i,1]
    // xp' = agg_dst(xu)@Wl[i,0] + xp@Wr[i,0] + bl[i,0]
    // xu' = agg_src(T) + xu@Wr[i,1] + bl[i,1]
    int cur = 0;
    const int nbGP = (NP + 127) / 128, nbGU = (NU + 127) / 128;
    for (int i = 0; i < 3; i++) {
        int relu = (i < 2) ? 1 : 0;
        const u16* WTl0 = WT + (size_t)(i * 2 + 0) * 2 * H * H;
        const u16* WTl1 = WT + (size_t)(i * 2 + 1) * 2 * H * H;
        const u16* WTr0 = WT + (size_t)(6 + i * 2 + 0) * 2 * H * H;
        const u16* WTr1 = WT + (size_t)(6 + i * 2 + 1) * 2 * H * H;
        aggregate_bf16<<<(NP + 15) / 16, 256, 0, stream>>>(XU[cur], rp_dst, col_dst, AGG_P, NP);
        gemm_p_layer<<<nbGP, 512, 0, stream>>>(
            XP[cur], AGG_P, WTl0, WTr0, WTl1, blv + (size_t)(i * 2 + 0) * H,
            T, XP[1 - cur], NP, relu);
        aggregate_bf16<<<(NU + 15) / 16, 256, 0, stream>>>(T, rp_src, col_src, AGG_U, NU);
        gemm_u_layer<<<nbGU, 512, 0, stream>>>(
            XU[cur], WTr1, AGG_U, blv + (size_t)(i * 2 + 1) * H, XU[1 - cur], NU, relu);
        cur = 1 - cur;
    }

    // ---- 4. link prediction ----
    predict<<<(EL + 15) / 16, 256, 0, stream>>>(XU[cur], XP[cur], lsrc, ldst, out, EL);
}